// Round 2
// baseline (378.447 us; speedup 1.0000x reference)
//
#include <hip/hip_runtime.h>
#include <hip/hip_bf16.h>
#include <stdint.h>

typedef __bf16 bf16;
typedef bf16 bf16x8 __attribute__((ext_vector_type(8)));
typedef float f32x4 __attribute__((ext_vector_type(4)));
typedef float f32x16 __attribute__((ext_vector_type(16)));

#define AS1 __attribute__((address_space(1)))
#define AS3 __attribute__((address_space(3)))

__device__ __forceinline__ void async_copy16(const void* g, void* l) {
    __builtin_amdgcn_global_load_lds((const AS1 uint32_t*)(g),
                                     (AS3 uint32_t*)(l), 16, 0, 0);
}

// ---------------- tiny prep kernels ----------------

// s[b,c] = style[b,:] . style_w[c,:] + style_b[c]   (one wave per output)
// block 0 also zeroes the 4 KiB DMA guard region (graph-safe memset).
__global__ void k_style(const float* __restrict__ style, const float* __restrict__ sw,
                        const float* __restrict__ sbias, float* __restrict__ s_out,
                        float* __restrict__ guard) {
    if (blockIdx.x == 0) {
#pragma unroll
        for (int j = 0; j < 4; ++j) guard[threadIdx.x + 256 * j] = 0.f;
    }
    int gw = (blockIdx.x * blockDim.x + threadIdx.x) >> 6;
    int lane = threadIdx.x & 63;
    if (gw >= 512) return;
    int b = gw >> 7, c = gw & 127;
    const float* st = style + b * 512;
    const float* wr = sw + c * 512;
    float a = 0.f;
#pragma unroll
    for (int j = 0; j < 8; ++j) a += st[lane + 64 * j] * wr[lane + 64 * j];
    for (int off = 32; off > 0; off >>= 1) a += __shfl_down(a, off, 64);
    if (lane == 0) s_out[gw] = a + sbias[c];
}

// sig_inv[b,o] = rsqrt( sum_i (sum_tap W[o,i,tap]^2) * s[b,i]^2 + 1e-8 )
__global__ void k_sig(const float* __restrict__ weight, const float* __restrict__ s,
                      float* __restrict__ sig) {
    int gw = (blockIdx.x * blockDim.x + threadIdx.x) >> 6;
    int lane = threadIdx.x & 63;
    if (gw >= 512) return;
    int b = gw >> 7, o = gw & 127;
    float a = 0.f;
#pragma unroll
    for (int j = 0; j < 2; ++j) {
        int i = lane + 64 * j;
        const float* wr = weight + ((size_t)o * 128 + i) * 9;
        float wsq = 0.f;
#pragma unroll
        for (int t = 0; t < 9; ++t) wsq += wr[t] * wr[t];
        float sv = s[b * 128 + i];
        a += wsq * sv * sv;
    }
    for (int off = 32; off > 0; off >>= 1) a += __shfl_down(a, off, 64);
    if (lane == 0) sig[gw] = rsqrtf(a + 1e-8f);
}

// repack weight fp32 [co][ci][9] -> bf16 W_t[chunk8][tap9][g2][co128][8ci]
__global__ void k_wt(const float* __restrict__ weight, bf16* __restrict__ wt) {
    int i = blockIdx.x * 256 + threadIdx.x;
    if (i >= 147456) return;
    int j = i & 7;
    int co = (i >> 3) & 127;
    int g = (i >> 10) & 1;
    int tap = (i >> 11) % 9;
    int chunk = (i >> 11) / 9;
    int ci = chunk * 16 + g * 8 + j;
    wt[i] = (bf16)weight[((size_t)co * 128 + ci) * 9 + tap];
}

// x fp32 [b][ci][h][w][t] * s[b][ci] -> bf16 x_t[b][h][w][t][ci]
__global__ void k_xt(const float* __restrict__ x, const float* __restrict__ s,
                     bf16* __restrict__ xt) {
    int E = blockIdx.x * 256 + threadIdx.x;   // 0..262143
    int b = E >> 16, e = E & 65535;
    const float* xb = x + (size_t)b * 8388608 + e;
    const float* sb = s + b * 128;
    bf16* dst = xt + (size_t)E * 128;
#pragma unroll 2
    for (int c0 = 0; c0 < 128; c0 += 8) {
        bf16x8 v;
#pragma unroll
        for (int j = 0; j < 8; ++j)
            v[j] = (bf16)(xb[(size_t)(c0 + j) * 65536] * sb[c0 + j]);
        *(bf16x8*)&dst[c0] = v;
    }
}

// ---------------- main MFMA conv kernel ----------------
// grid (8 wblk, 64 h, 4 b); block 256 = 4 waves; tile 128co x 128elem (8w x 16t)
__global__ __launch_bounds__(256, 3) void conv_main(
    const bf16* __restrict__ xt, const bf16* __restrict__ wt,
    const float* __restrict__ sig_inv, const float* __restrict__ npar,
    const float* __restrict__ bpar, const float* __restrict__ noise,
    const bf16* __restrict__ guard, float* __restrict__ out) {
    __shared__ bf16 Wl[9 * 2 * 128 * 8];   // 36864 B  [tap][g][co][8ci]
    __shared__ bf16 Xl[3 * 2 * 160 * 8];   // 15360 B  [dh][g][elem160][8ci]

    const int tid = threadIdx.x;
    const int wid = tid >> 6, lane = tid & 63;
    const int l31 = lane & 31, lhi = lane >> 5;
    const int wm = wid & 1, wn = wid >> 1;
    const int w0 = blockIdx.x * 8;
    const int h = blockIdx.y;
    const int b = blockIdx.z;
    const size_t bHW = (size_t)b * 65536;

    f32x16 acc[2][2] = {};

    for (int chunk = 0; chunk < 8; ++chunk) {
        // stage W chunk: 2304 x 16B, contiguous, all lanes active
        {
            const bf16* wsrc = wt + (size_t)chunk * 18432;
#pragma unroll
            for (int it = 0; it < 9; ++it) {
                int u = it * 256 + tid;
                async_copy16(wsrc + (size_t)u * 8, &Wl[u * 8]);
            }
        }
        // stage X chunk: 960 x 16B; OOB lanes fetch from the zero guard so the
        // wave stays fully active (global_load_lds LDS base is wave-uniform).
#pragma unroll
        for (int it = 0; it < 4; ++it) {
            int u = it * 256 + tid;
            if (u < 960) {               // wave-uniform (tail wave skips whole)
                int dh = u / 320;
                int rem = u - dh * 320;
                int g = rem / 160;
                int e = rem - g * 160;
                int ha = h - 1 + dh;
                int wa = w0 - 1 + (e >> 4);
                bool ok = ((unsigned)ha < 64u) && ((unsigned)wa < 64u);
                const bf16* gsrc = ok
                    ? xt + ((bHW + (size_t)((ha * 64 + wa) * 16 + (e & 15))) * 128 +
                            chunk * 16 + g * 8)
                    : guard;
                async_copy16(gsrc, &Xl[u * 8]);
            }
        }
        __syncthreads();

#pragma unroll
        for (int tap = 0; tap < 9; ++tap) {
            const int dh = tap / 3, dw = tap % 3;
            const bf16* wb = &Wl[((tap * 2 + lhi) * 128 + wm * 64 + l31) * 8];
            bf16x8 a0 = *(const bf16x8*)&wb[0];
            bf16x8 a1 = *(const bf16x8*)&wb[32 * 8];
            const bf16* xb = &Xl[((dh * 2 + lhi) * 160 + dw * 16 + wn * 64 + l31) * 8];
            bf16x8 b0 = *(const bf16x8*)&xb[0];
            bf16x8 b1 = *(const bf16x8*)&xb[32 * 8];
            acc[0][0] = __builtin_amdgcn_mfma_f32_32x32x16_bf16(a0, b0, acc[0][0], 0, 0, 0);
            acc[0][1] = __builtin_amdgcn_mfma_f32_32x32x16_bf16(a0, b1, acc[0][1], 0, 0, 0);
            acc[1][0] = __builtin_amdgcn_mfma_f32_32x32x16_bf16(a1, b0, acc[1][0], 0, 0, 0);
            acc[1][1] = __builtin_amdgcn_mfma_f32_32x32x16_bf16(a1, b1, acc[1][1], 0, 0, 0);
        }
        __syncthreads();
    }

    // epilogue: D col = lane&31 (elem), row = (reg&3)+8*(reg>>2)+4*lhi (co)
    const int ebase = wn * 64 + l31;
    const size_t nbase = bHW + (size_t)h * 1024 + w0 * 16;
    float ns0 = noise[nbase + ebase];
    float ns1 = noise[nbase + ebase + 32];
#pragma unroll
    for (int fm = 0; fm < 2; ++fm) {
        int cob = wm * 64 + fm * 32 + 4 * lhi;
#pragma unroll
        for (int q = 0; q < 4; ++q) {
            int co4 = cob + 8 * q;
            f32x4 sg = *(const f32x4*)&sig_inv[b * 128 + co4];
            f32x4 np4 = *(const f32x4*)&npar[co4];
            f32x4 bp4 = *(const f32x4*)&bpar[co4];
#pragma unroll
            for (int r = 0; r < 4; ++r) {
                int co = co4 + r;
                float* orow = out + ((size_t)(b * 128 + co) * 64 + h) * 1024 + w0 * 16;
#pragma unroll
                for (int fn = 0; fn < 2; ++fn) {
                    float v = acc[fm][fn][q * 4 + r];
                    float nse = fn ? ns1 : ns0;
                    orow[wn * 64 + fn * 32 + l31] = v * sg[r] + np4[r] * nse + bp4[r];
                }
            }
        }
    }
}

// ---------------- fp32 fallback (ws too small) ----------------
__global__ void k_naive(const float* __restrict__ x, const float* __restrict__ weight,
                        const float* __restrict__ s, const float* __restrict__ sig,
                        const float* __restrict__ npar, const float* __restrict__ bpar,
                        const float* __restrict__ noise, float* __restrict__ out) {
    size_t o = (size_t)blockIdx.x * 256 + threadIdx.x;
    int t = o & 15, w = (o >> 4) & 63, h = (o >> 10) & 63;
    int co = (o >> 16) & 127, b = (int)(o >> 23);
    float a = 0.f;
    for (int ci = 0; ci < 128; ++ci) {
        const float* xr = x + (size_t)(b * 128 + ci) * 65536;
        const float* wr = weight + ((size_t)co * 128 + ci) * 9;
        float p = 0.f;
#pragma unroll
        for (int kh = 0; kh < 3; ++kh) {
            int ha = h + kh - 1;
            if ((unsigned)ha >= 64u) continue;
#pragma unroll
            for (int kw = 0; kw < 3; ++kw) {
                int wa = w + kw - 1;
                if ((unsigned)wa >= 64u) continue;
                p += xr[(ha * 64 + wa) * 16 + t] * wr[kh * 3 + kw];
            }
        }
        a += p * s[b * 128 + ci];
    }
    int E = b * 65536 + (h * 64 + w) * 16 + t;
    out[o] = a * sig[b * 128 + co] + npar[co] * noise[E] + bpar[co];
}

// ---------------- host ----------------
extern "C" void kernel_launch(void* const* d_in, const int* in_sizes, int n_in,
                              void* d_out, int out_size, void* d_ws, size_t ws_size,
                              hipStream_t stream) {
    const float* x      = (const float*)d_in[0];
    const float* style  = (const float*)d_in[1];
    const float* noise  = (const float*)d_in[2];
    const float* weight = (const float*)d_in[3];
    const float* sw     = (const float*)d_in[4];
    const float* sb     = (const float*)d_in[5];
    const float* npar   = (const float*)d_in[6];
    const float* bpar   = (const float*)d_in[7];
    float* out = (float*)d_out;

    float* s_buf   = (float*)d_ws;                         // 512 f32
    float* sig_buf = s_buf + 512;                          // 512 f32
    float* guard   = (float*)((char*)d_ws + 4096);         // 4096 B zeros
    bf16*  wt      = (bf16*)((char*)d_ws + 8192);          // 294912 B
    bf16*  xt      = (bf16*)((char*)d_ws + 8192 + 294912); // 67108864 B
    const size_t NEED = 8192 + 294912 + 67108864ull;

    k_style<<<dim3(128), dim3(256), 0, stream>>>(style, sw, sb, s_buf, guard);
    k_sig<<<dim3(128), dim3(256), 0, stream>>>(weight, s_buf, sig_buf);
    if (ws_size >= NEED) {
        k_wt<<<dim3(576), dim3(256), 0, stream>>>(weight, wt);
        k_xt<<<dim3(1024), dim3(256), 0, stream>>>(x, s_buf, xt);
        conv_main<<<dim3(8, 64, 4), dim3(256), 0, stream>>>(
            xt, wt, sig_buf, npar, bpar, noise, (const bf16*)guard, out);
    } else {
        k_naive<<<dim3(131072), dim3(256), 0, stream>>>(
            x, weight, s_buf, sig_buf, npar, bpar, noise, out);
    }
}

// Round 3
// 327.896 us; speedup vs baseline: 1.1542x; 1.1542x over previous
//
#include <hip/hip_runtime.h>
#include <hip/hip_bf16.h>
#include <stdint.h>

typedef __bf16 bf16;
typedef bf16 bf16x8 __attribute__((ext_vector_type(8)));
typedef float f32x4 __attribute__((ext_vector_type(4)));
typedef float f32x16 __attribute__((ext_vector_type(16)));

#define AS1 __attribute__((address_space(1)))
#define AS3 __attribute__((address_space(3)))

__device__ __forceinline__ void async_copy16(const void* g, void* l) {
    __builtin_amdgcn_global_load_lds((const AS1 uint32_t*)(g),
                                     (AS3 uint32_t*)(l), 16, 0, 0);
}

// ---------------- tiny prep kernels ----------------

// s[b,c] = style[b,:] . style_w[c,:] + style_b[c]; block 0 zeroes DMA guard.
__global__ void k_style(const float* __restrict__ style, const float* __restrict__ sw,
                        const float* __restrict__ sbias, float* __restrict__ s_out,
                        float* __restrict__ guard) {
    if (blockIdx.x == 0) {
#pragma unroll
        for (int j = 0; j < 4; ++j) guard[threadIdx.x + 256 * j] = 0.f;
    }
    int gw = (blockIdx.x * blockDim.x + threadIdx.x) >> 6;
    int lane = threadIdx.x & 63;
    if (gw >= 512) return;
    int b = gw >> 7, c = gw & 127;
    const float* st = style + b * 512;
    const float* wr = sw + c * 512;
    float a = 0.f;
#pragma unroll
    for (int j = 0; j < 8; ++j) a += st[lane + 64 * j] * wr[lane + 64 * j];
    for (int off = 32; off > 0; off >>= 1) a += __shfl_down(a, off, 64);
    if (lane == 0) s_out[gw] = a + sbias[c];
}

// sig_inv[b,o] = rsqrt( sum_i (sum_tap W[o,i,tap]^2) * s[b,i]^2 + 1e-8 )
__global__ void k_sig(const float* __restrict__ weight, const float* __restrict__ s,
                      float* __restrict__ sig) {
    int gw = (blockIdx.x * blockDim.x + threadIdx.x) >> 6;
    int lane = threadIdx.x & 63;
    if (gw >= 512) return;
    int b = gw >> 7, o = gw & 127;
    float a = 0.f;
#pragma unroll
    for (int j = 0; j < 2; ++j) {
        int i = lane + 64 * j;
        const float* wr = weight + ((size_t)o * 128 + i) * 9;
        float wsq = 0.f;
#pragma unroll
        for (int t = 0; t < 9; ++t) wsq += wr[t] * wr[t];
        float sv = s[b * 128 + i];
        a += wsq * sv * sv;
    }
    for (int off = 32; off > 0; off >>= 1) a += __shfl_down(a, off, 64);
    if (lane == 0) sig[gw] = rsqrtf(a + 1e-8f);
}

// repack weight fp32 [co][ci][9] -> bf16 wt[chunk8][tap9][g2][co128][8ci]
__global__ void k_wt(const float* __restrict__ weight, bf16* __restrict__ wt) {
    int i = blockIdx.x * 256 + threadIdx.x;
    if (i >= 147456) return;
    int j = i & 7;
    int co = (i >> 3) & 127;
    int g = (i >> 10) & 1;
    int tap = (i >> 11) % 9;
    int chunk = (i >> 11) / 9;
    int ci = chunk * 16 + g * 8 + j;
    wt[i] = (bf16)weight[((size_t)co * 128 + ci) * 9 + tap];
}

// x fp32 [b][ci][hwt] * s[b][ci] -> bf16 xt[b][g=ci>>3][e=hwt][8ci]
// reads coalesced (256B/wave/plane); writes contiguous 16B/lane (1KB/wave).
__global__ void k_xt(const float* __restrict__ x, const float* __restrict__ s,
                     bf16* __restrict__ xt) {
    int E = blockIdx.x * 256 + threadIdx.x;   // 0..262143
    int b = E >> 16, e = E & 65535;
    const float* xb = x + (size_t)b * 8388608 + e;
    const float* sb = s + b * 128;
#pragma unroll 4
    for (int g = 0; g < 16; ++g) {
        bf16x8 v;
#pragma unroll
        for (int j = 0; j < 8; ++j)
            v[j] = (bf16)(xb[(size_t)(g * 8 + j) * 65536] * sb[g * 8 + j]);
        *(bf16x8*)(xt + ((((size_t)b * 16 + g) << 16) + e) * 8) = v;
    }
}

// ---------------- main MFMA conv kernel ----------------
// grid (4 wblk, 64 h, 4 b); block 256 = 4 waves; tile 128co x 256elem (16w x 16t)
// W operand: global->VGPR (L2-resident); X operand: global_load_lds staged.
__global__ __launch_bounds__(256, 2) void conv_main(
    const bf16* __restrict__ xt, const bf16* __restrict__ wt,
    const float* __restrict__ sig_inv, const float* __restrict__ npar,
    const float* __restrict__ bpar, const float* __restrict__ noise,
    const bf16* __restrict__ guard, float* __restrict__ out) {
    __shared__ bf16 Xl[3 * 2 * 288 * 8];   // 27648 B  [dh][g][e288][8ci]

    const int tid = threadIdx.x;
    const int wid = tid >> 6, lane = tid & 63;
    const int l31 = lane & 31, lhi = lane >> 5;
    const int wm = wid & 1, wn = wid >> 1;
    const int w0 = blockIdx.x * 16;
    const int h = blockIdx.y;
    const int b = blockIdx.z;
    const size_t bHW = (size_t)b * 65536;

    f32x16 acc[2][4] = {};

    for (int chunk = 0; chunk < 8; ++chunk) {
        // stage X chunk: 1728 x 16B cells [dh3][g2][e288]; rows are 2560B
        // contiguous runs in xt. OOB lanes fetch the zero guard (wave stays
        // fully active: global_load_lds LDS base is wave-uniform).
#pragma unroll
        for (int it = 0; it < 7; ++it) {
            int u = it * 256 + tid;
            if (u < 1728) {              // 27*64: wave-uniform cut
                int dh = u / 576;
                int rem = u - dh * 576;
                int g = rem / 288;
                int e = rem - g * 288;
                int ha = h - 1 + dh;
                int wa = w0 - 1 + (e >> 4);
                bool ok = ((unsigned)ha < 64u) & ((unsigned)wa < 64u);
                int E = (ha * 64 + wa) * 16 + (e & 15);
                const bf16* gsrc = ok
                    ? xt + ((((size_t)b * 16 + chunk * 2 + g) << 16) + E) * 8
                    : guard;
                async_copy16(gsrc, &Xl[u * 8]);
            }
        }
        __syncthreads();

#pragma unroll
        for (int tap = 0; tap < 9; ++tap) {
            const int dh = tap / 3, dw = tap % 3;
            const bf16* wg = wt +
                ((size_t)((chunk * 9 + tap) * 2 + lhi) * 128 + wm * 64 + l31) * 8;
            bf16x8 a0 = *(const bf16x8*)&wg[0];
            bf16x8 a1 = *(const bf16x8*)&wg[32 * 8];
            const bf16* xb = &Xl[((dh * 2 + lhi) * 288 + dw * 16 + wn * 128 + l31) * 8];
            bf16x8 b0 = *(const bf16x8*)&xb[0];
            bf16x8 b1 = *(const bf16x8*)&xb[32 * 8];
            bf16x8 b2 = *(const bf16x8*)&xb[64 * 8];
            bf16x8 b3 = *(const bf16x8*)&xb[96 * 8];
            acc[0][0] = __builtin_amdgcn_mfma_f32_32x32x16_bf16(a0, b0, acc[0][0], 0, 0, 0);
            acc[0][1] = __builtin_amdgcn_mfma_f32_32x32x16_bf16(a0, b1, acc[0][1], 0, 0, 0);
            acc[0][2] = __builtin_amdgcn_mfma_f32_32x32x16_bf16(a0, b2, acc[0][2], 0, 0, 0);
            acc[0][3] = __builtin_amdgcn_mfma_f32_32x32x16_bf16(a0, b3, acc[0][3], 0, 0, 0);
            acc[1][0] = __builtin_amdgcn_mfma_f32_32x32x16_bf16(a1, b0, acc[1][0], 0, 0, 0);
            acc[1][1] = __builtin_amdgcn_mfma_f32_32x32x16_bf16(a1, b1, acc[1][1], 0, 0, 0);
            acc[1][2] = __builtin_amdgcn_mfma_f32_32x32x16_bf16(a1, b2, acc[1][2], 0, 0, 0);
            acc[1][3] = __builtin_amdgcn_mfma_f32_32x32x16_bf16(a1, b3, acc[1][3], 0, 0, 0);
        }
        __syncthreads();
    }

    // epilogue: D col = lane&31 (elem), row = (reg&3)+8*(reg>>2)+4*lhi (co)
    const size_t ebase = bHW + (size_t)h * 1024 + w0 * 16 + wn * 128;
    float ns[4];
#pragma unroll
    for (int nf = 0; nf < 4; ++nf) ns[nf] = noise[ebase + nf * 32 + l31];
#pragma unroll
    for (int fm = 0; fm < 2; ++fm) {
        int cob = wm * 64 + fm * 32 + 4 * lhi;
#pragma unroll
        for (int q = 0; q < 4; ++q) {
            int co4 = cob + 8 * q;
            f32x4 sg = *(const f32x4*)&sig_inv[b * 128 + co4];
            f32x4 np4 = *(const f32x4*)&npar[co4];
            f32x4 bp4 = *(const f32x4*)&bpar[co4];
#pragma unroll
            for (int r = 0; r < 4; ++r) {
                int co = co4 + r;
                float* orow = out + ((size_t)(b * 128 + co) * 64 + h) * 1024 +
                              w0 * 16 + wn * 128;
#pragma unroll
                for (int nf = 0; nf < 4; ++nf) {
                    float v = acc[fm][nf][q * 4 + r];
                    orow[nf * 32 + l31] = v * sg[r] + np4[r] * ns[nf] + bp4[r];
                }
            }
        }
    }
}

// ---------------- fp32 fallback (ws too small) ----------------
__global__ void k_naive(const float* __restrict__ x, const float* __restrict__ weight,
                        const float* __restrict__ s, const float* __restrict__ sig,
                        const float* __restrict__ npar, const float* __restrict__ bpar,
                        const float* __restrict__ noise, float* __restrict__ out) {
    size_t o = (size_t)blockIdx.x * 256 + threadIdx.x;
    int t = o & 15, w = (o >> 4) & 63, h = (o >> 10) & 63;
    int co = (o >> 16) & 127, b = (int)(o >> 23);
    float a = 0.f;
    for (int ci = 0; ci < 128; ++ci) {
        const float* xr = x + (size_t)(b * 128 + ci) * 65536;
        const float* wr = weight + ((size_t)co * 128 + ci) * 9;
        float p = 0.f;
#pragma unroll
        for (int kh = 0; kh < 3; ++kh) {
            int ha = h + kh - 1;
            if ((unsigned)ha >= 64u) continue;
#pragma unroll
            for (int kw = 0; kw < 3; ++kw) {
                int wa = w + kw - 1;
                if ((unsigned)wa >= 64u) continue;
                p += xr[(ha * 64 + wa) * 16 + t] * wr[kh * 3 + kw];
            }
        }
        a += p * s[b * 128 + ci];
    }
    int E = b * 65536 + (h * 64 + w) * 16 + t;
    out[o] = a * sig[b * 128 + co] + npar[co] * noise[E] + bpar[co];
}

// ---------------- host ----------------
extern "C" void kernel_launch(void* const* d_in, const int* in_sizes, int n_in,
                              void* d_out, int out_size, void* d_ws, size_t ws_size,
                              hipStream_t stream) {
    const float* x      = (const float*)d_in[0];
    const float* style  = (const float*)d_in[1];
    const float* noise  = (const float*)d_in[2];
    const float* weight = (const float*)d_in[3];
    const float* sw     = (const float*)d_in[4];
    const float* sb     = (const float*)d_in[5];
    const float* npar   = (const float*)d_in[6];
    const float* bpar   = (const float*)d_in[7];
    float* out = (float*)d_out;

    float* s_buf   = (float*)d_ws;                         // 512 f32
    float* sig_buf = s_buf + 512;                          // 512 f32
    float* guard   = (float*)((char*)d_ws + 4096);         // 4096 B zeros
    bf16*  wt      = (bf16*)((char*)d_ws + 8192);          // 294912 B
    bf16*  xt      = (bf16*)((char*)d_ws + 8192 + 294912); // 67108864 B
    const size_t NEED = 8192 + 294912 + 67108864ull;

    k_style<<<dim3(128), dim3(256), 0, stream>>>(style, sw, sb, s_buf, guard);
    k_sig<<<dim3(128), dim3(256), 0, stream>>>(weight, s_buf, sig_buf);
    if (ws_size >= NEED) {
        k_wt<<<dim3(576), dim3(256), 0, stream>>>(weight, wt);
        k_xt<<<dim3(1024), dim3(256), 0, stream>>>(x, s_buf, xt);
        conv_main<<<dim3(4, 64, 4), dim3(256), 0, stream>>>(
            xt, wt, sig_buf, npar, bpar, noise, (const bf16*)guard, out);
    } else {
        k_naive<<<dim3(131072), dim3(256), 0, stream>>>(
            x, weight, s_buf, sig_buf, npar, bpar, noise, out);
    }
}

// Round 4
// 325.098 us; speedup vs baseline: 1.1641x; 1.0086x over previous
//
#include <hip/hip_runtime.h>
#include <hip/hip_bf16.h>
#include <stdint.h>

typedef __bf16 bf16;
typedef bf16 bf16x8 __attribute__((ext_vector_type(8)));
typedef float f32x4 __attribute__((ext_vector_type(4)));
typedef float f32x16 __attribute__((ext_vector_type(16)));

#define AS1 __attribute__((address_space(1)))
#define AS3 __attribute__((address_space(3)))

__device__ __forceinline__ void async_copy16(const void* g, void* l) {
    __builtin_amdgcn_global_load_lds((const AS1 uint32_t*)(g),
                                     (AS3 uint32_t*)(l), 16, 0, 0);
}

// ---------------- tiny prep kernels ----------------

// s[b,c] = style[b,:] . style_w[c,:] + style_b[c]; block 0 zeroes DMA guard.
__global__ void k_style(const float* __restrict__ style, const float* __restrict__ sw,
                        const float* __restrict__ sbias, float* __restrict__ s_out,
                        float* __restrict__ guard) {
    if (blockIdx.x == 0) {
#pragma unroll
        for (int j = 0; j < 4; ++j) guard[threadIdx.x + 256 * j] = 0.f;
    }
    int gw = (blockIdx.x * blockDim.x + threadIdx.x) >> 6;
    int lane = threadIdx.x & 63;
    if (gw >= 512) return;
    int b = gw >> 7, c = gw & 127;
    const float* st = style + b * 512;
    const float* wr = sw + c * 512;
    float a = 0.f;
#pragma unroll
    for (int j = 0; j < 8; ++j) a += st[lane + 64 * j] * wr[lane + 64 * j];
    for (int off = 32; off > 0; off >>= 1) a += __shfl_down(a, off, 64);
    if (lane == 0) s_out[gw] = a + sbias[c];
}

// sig_inv[b,o] = rsqrt( sum_i (sum_tap W[o,i,tap]^2) * s[b,i]^2 + 1e-8 )
__global__ void k_sig(const float* __restrict__ weight, const float* __restrict__ s,
                      float* __restrict__ sig) {
    int gw = (blockIdx.x * blockDim.x + threadIdx.x) >> 6;
    int lane = threadIdx.x & 63;
    if (gw >= 512) return;
    int b = gw >> 7, o = gw & 127;
    float a = 0.f;
#pragma unroll
    for (int j = 0; j < 2; ++j) {
        int i = lane + 64 * j;
        const float* wr = weight + ((size_t)o * 128 + i) * 9;
        float wsq = 0.f;
#pragma unroll
        for (int t = 0; t < 9; ++t) wsq += wr[t] * wr[t];
        float sv = s[b * 128 + i];
        a += wsq * sv * sv;
    }
    for (int off = 32; off > 0; off >>= 1) a += __shfl_down(a, off, 64);
    if (lane == 0) sig[gw] = rsqrtf(a + 1e-8f);
}

// repack weight fp32 [co][ci][9] -> bf16 wt[chunk8][tap9][g2][co128][8ci]
__global__ void k_wt(const float* __restrict__ weight, bf16* __restrict__ wt) {
    int i = blockIdx.x * 256 + threadIdx.x;
    if (i >= 147456) return;
    int j = i & 7;
    int co = (i >> 3) & 127;
    int g = (i >> 10) & 1;
    int tap = (i >> 11) % 9;
    int chunk = (i >> 11) / 9;
    int ci = chunk * 16 + g * 8 + j;
    wt[i] = (bf16)weight[((size_t)co * 128 + ci) * 9 + tap];
}

// x fp32 [b][ci][hwt] * s[b][ci] -> bf16 xt[b][g=ci>>3][e=hwt][8ci]
__global__ void k_xt(const float* __restrict__ x, const float* __restrict__ s,
                     bf16* __restrict__ xt) {
    int E = blockIdx.x * 256 + threadIdx.x;   // 0..262143
    int b = E >> 16, e = E & 65535;
    const float* xb = x + (size_t)b * 8388608 + e;
    const float* sb = s + b * 128;
#pragma unroll 4
    for (int g = 0; g < 16; ++g) {
        bf16x8 v;
#pragma unroll
        for (int j = 0; j < 8; ++j)
            v[j] = (bf16)(xb[(size_t)(g * 8 + j) * 65536] * sb[g * 8 + j]);
        *(bf16x8*)(xt + ((((size_t)b * 16 + g) << 16) + e) * 8) = v;
    }
}

// ---------------- main MFMA conv kernel ----------------
// grid (4 wblk, 64 h, 4 b); block 256 = 4 waves; tile 128co x 256elem (16w x 16t)
// W: global->VGPR (L2-hot). X: double-buffered global_load_lds, staged one
// chunk ahead so the barrier drain overlaps the 2304-cyc compute phase.
__global__ __launch_bounds__(256, 2) void conv_main(
    const bf16* __restrict__ xt, const bf16* __restrict__ wt,
    const float* __restrict__ sig_inv, const float* __restrict__ npar,
    const float* __restrict__ bpar, const float* __restrict__ noise,
    const bf16* __restrict__ guard, float* __restrict__ out) {
    __shared__ bf16 Xl[2][1728 * 8];   // 2 x 27648 B  [dh3][g2][e288][8ci]

    const int tid = threadIdx.x;
    const int lane = tid & 63;
    const int l31 = lane & 31, lhi = lane >> 5;
    const int wm = (tid >> 6) & 1, wn = tid >> 7;
    const int w0 = blockIdx.x * 16;
    const int h = blockIdx.y;
    const int b = blockIdx.z;
    const size_t bHW = (size_t)b * 65536;

    // staging of one X chunk into buf: 1728 16B cells, waves fully active
    // (OOB lanes fetch the zero guard; LDS base of global_load_lds is
    // wave-uniform so no lane may be masked off).
    auto stage = [&](int chunk, bf16* buf) {
#pragma unroll
        for (int it = 0; it < 7; ++it) {
            int u = it * 256 + tid;
            if (u < 1728) {              // 27 waves: wave-uniform cut
                int dh = u / 576;
                int rem = u - dh * 576;
                int g = rem / 288;
                int e = rem - g * 288;
                int ha = h - 1 + dh;
                int wa = w0 - 1 + (e >> 4);
                bool ok = ((unsigned)ha < 64u) & ((unsigned)wa < 64u);
                int E = (ha * 64 + wa) * 16 + (e & 15);
                const bf16* gsrc = ok
                    ? xt + ((((size_t)b * 16 + chunk * 2 + g) << 16) + E) * 8
                    : guard;
                async_copy16(gsrc, &buf[u * 8]);
            }
        }
    };

    f32x16 acc[2][4] = {};

    // prefetch epilogue noise early (independent of K-loop)
    const size_t ebase = bHW + (size_t)h * 1024 + w0 * 16 + wn * 128;
    float ns[4];
#pragma unroll
    for (int nf = 0; nf < 4; ++nf) ns[nf] = noise[ebase + nf * 32 + l31];

    stage(0, Xl[0]);

    for (int chunk = 0; chunk < 8; ++chunk) {
        __syncthreads();                       // buf[chunk] DMAs are done;
                                               // buf[chunk+1]'s old readers done
        if (chunk < 7) stage(chunk + 1, Xl[(chunk + 1) & 1]);
        __builtin_amdgcn_sched_barrier(0);     // pin DMA issue before compute
        const bf16* Xb = Xl[chunk & 1];

#pragma unroll
        for (int tap = 0; tap < 9; ++tap) {
            const int dh = tap / 3, dw = tap % 3;
            const bf16* wg = wt +
                ((size_t)((chunk * 9 + tap) * 2 + lhi) * 128 + wm * 64 + l31) * 8;
            bf16x8 a0 = *(const bf16x8*)&wg[0];
            bf16x8 a1 = *(const bf16x8*)&wg[32 * 8];
            const bf16* xb = &Xb[((dh * 2 + lhi) * 288 + dw * 16 + wn * 128 + l31) * 8];
            bf16x8 b0 = *(const bf16x8*)&xb[0];
            bf16x8 b1 = *(const bf16x8*)&xb[32 * 8];
            bf16x8 b2 = *(const bf16x8*)&xb[64 * 8];
            bf16x8 b3 = *(const bf16x8*)&xb[96 * 8];
            acc[0][0] = __builtin_amdgcn_mfma_f32_32x32x16_bf16(a0, b0, acc[0][0], 0, 0, 0);
            acc[0][1] = __builtin_amdgcn_mfma_f32_32x32x16_bf16(a0, b1, acc[0][1], 0, 0, 0);
            acc[0][2] = __builtin_amdgcn_mfma_f32_32x32x16_bf16(a0, b2, acc[0][2], 0, 0, 0);
            acc[0][3] = __builtin_amdgcn_mfma_f32_32x32x16_bf16(a0, b3, acc[0][3], 0, 0, 0);
            acc[1][0] = __builtin_amdgcn_mfma_f32_32x32x16_bf16(a1, b0, acc[1][0], 0, 0, 0);
            acc[1][1] = __builtin_amdgcn_mfma_f32_32x32x16_bf16(a1, b1, acc[1][1], 0, 0, 0);
            acc[1][2] = __builtin_amdgcn_mfma_f32_32x32x16_bf16(a1, b2, acc[1][2], 0, 0, 0);
            acc[1][3] = __builtin_amdgcn_mfma_f32_32x32x16_bf16(a1, b3, acc[1][3], 0, 0, 0);
        }
    }

    // epilogue: D col = lane&31 (elem), row = (reg&3)+8*(reg>>2)+4*lhi (co)
#pragma unroll
    for (int fm = 0; fm < 2; ++fm) {
        int cob = wm * 64 + fm * 32 + 4 * lhi;
#pragma unroll
        for (int q = 0; q < 4; ++q) {
            int co4 = cob + 8 * q;
            f32x4 sg = *(const f32x4*)&sig_inv[b * 128 + co4];
            f32x4 np4 = *(const f32x4*)&npar[co4];
            f32x4 bp4 = *(const f32x4*)&bpar[co4];
#pragma unroll
            for (int r = 0; r < 4; ++r) {
                int co = co4 + r;
                float* orow = out + ((size_t)(b * 128 + co) * 64 + h) * 1024 +
                              w0 * 16 + wn * 128;
#pragma unroll
                for (int nf = 0; nf < 4; ++nf) {
                    float v = acc[fm][nf][q * 4 + r];
                    orow[nf * 32 + l31] = v * sg[r] + np4[r] * ns[nf] + bp4[r];
                }
            }
        }
    }
}

// ---------------- fp32 fallback (ws too small) ----------------
__global__ void k_naive(const float* __restrict__ x, const float* __restrict__ weight,
                        const float* __restrict__ s, const float* __restrict__ sig,
                        const float* __restrict__ npar, const float* __restrict__ bpar,
                        const float* __restrict__ noise, float* __restrict__ out) {
    size_t o = (size_t)blockIdx.x * 256 + threadIdx.x;
    int t = o & 15, w = (o >> 4) & 63, h = (o >> 10) & 63;
    int co = (o >> 16) & 127, b = (int)(o >> 23);
    float a = 0.f;
    for (int ci = 0; ci < 128; ++ci) {
        const float* xr = x + (size_t)(b * 128 + ci) * 65536;
        const float* wr = weight + ((size_t)co * 128 + ci) * 9;
        float p = 0.f;
#pragma unroll
        for (int kh = 0; kh < 3; ++kh) {
            int ha = h + kh - 1;
            if ((unsigned)ha >= 64u) continue;
#pragma unroll
            for (int kw = 0; kw < 3; ++kw) {
                int wa = w + kw - 1;
                if ((unsigned)wa >= 64u) continue;
                p += xr[(ha * 64 + wa) * 16 + t] * wr[kh * 3 + kw];
            }
        }
        a += p * s[b * 128 + ci];
    }
    int E = b * 65536 + (h * 64 + w) * 16 + t;
    out[o] = a * sig[b * 128 + co] + npar[co] * noise[E] + bpar[co];
}

// ---------------- host ----------------
extern "C" void kernel_launch(void* const* d_in, const int* in_sizes, int n_in,
                              void* d_out, int out_size, void* d_ws, size_t ws_size,
                              hipStream_t stream) {
    const float* x      = (const float*)d_in[0];
    const float* style  = (const float*)d_in[1];
    const float* noise  = (const float*)d_in[2];
    const float* weight = (const float*)d_in[3];
    const float* sw     = (const float*)d_in[4];
    const float* sb     = (const float*)d_in[5];
    const float* npar   = (const float*)d_in[6];
    const float* bpar   = (const float*)d_in[7];
    float* out = (float*)d_out;

    float* s_buf   = (float*)d_ws;                         // 512 f32
    float* sig_buf = s_buf + 512;                          // 512 f32
    float* guard   = (float*)((char*)d_ws + 4096);         // 4096 B zeros
    bf16*  wt      = (bf16*)((char*)d_ws + 8192);          // 294912 B
    bf16*  xt      = (bf16*)((char*)d_ws + 8192 + 294912); // 67108864 B
    const size_t NEED = 8192 + 294912 + 67108864ull;

    k_style<<<dim3(128), dim3(256), 0, stream>>>(style, sw, sb, s_buf, guard);
    k_sig<<<dim3(128), dim3(256), 0, stream>>>(weight, s_buf, sig_buf);
    if (ws_size >= NEED) {
        k_wt<<<dim3(576), dim3(256), 0, stream>>>(weight, wt);
        k_xt<<<dim3(1024), dim3(256), 0, stream>>>(x, s_buf, xt);
        conv_main<<<dim3(4, 64, 4), dim3(256), 0, stream>>>(
            xt, wt, sig_buf, npar, bpar, noise, (const bf16*)guard, out);
    } else {
        k_naive<<<dim3(131072), dim3(256), 0, stream>>>(
            x, weight, s_buf, sig_buf, npar, bpar, noise, out);
    }
}